// Round 6
// baseline (353.379 us; speedup 1.0000x reference)
//
#include <hip/hip_runtime.h>

#define BB 4
#define NN 1024
#define KK 9
#define C  32
#define CM 128
#define M  (BB*NN)       // 4096 rows
#define EPSB 1e-5f
#define SLOPE 0.01f

#define GB 512           // grid blocks
#define SCH 4            // n-chunks (part slots)
#define NCH 256          // n per chunk
#define KPAD 296         // padded row stride (f16) for comp_w tiles
#define CHUNK_F16 (32*KPAD)   // 9472 f16 per (b,nc,sub) tile

// barrier memory: arrive flag(p,b) at (p*GB+b)*4 ints (16B stride);
// done flag(p,b) at (4*GB + p*GB + b)*4. All zeroed by memset pre-launch.
#define BAR_INTS (2*4*GB*4)

typedef _Float16 f16x8 __attribute__((ext_vector_type(8)));
typedef _Float16 f16x4 __attribute__((ext_vector_type(4)));
typedef float    f32x4 __attribute__((ext_vector_type(4)));

__device__ __forceinline__ float leaky(float x){ return x > 0.f ? x : SLOPE*x; }

// RMW-free grid barrier. r4/r5 evidence: same-word agent-scope fetch_add
// fan-in costs ~150 cyc per serialized op (512-chain ~= 33us). Here:
// arrival = release-STORE to a per-block slot (no serialization);
// block 0 sweeps all slots (256 thr x 2), then broadcasts per-block
// done-flags; consumers spin on their own line. Release/acquire chain
// (producer->block0->consumer) gives cross-XCD visibility transitively.
__device__ __forceinline__ void gridbar(int* bar, int phase, bool spin){
  __syncthreads();
  if (threadIdx.x == 0){
    __hip_atomic_store(&bar[(phase*GB + blockIdx.x)*4], 1,
                       __ATOMIC_RELEASE, __HIP_MEMORY_SCOPE_AGENT);
  }
  if (blockIdx.x == 0){
    int s0 = (phase*GB + threadIdx.x*2)*4;
    for (;;){
      int a = __hip_atomic_load(&bar[s0],   __ATOMIC_ACQUIRE, __HIP_MEMORY_SCOPE_AGENT);
      int b = __hip_atomic_load(&bar[s0+4], __ATOMIC_ACQUIRE, __HIP_MEMORY_SCOPE_AGENT);
      if (__syncthreads_count((a + b) < 2) == 0) break;
      __builtin_amdgcn_s_sleep(4);
    }
    for (int b2 = threadIdx.x; b2 < GB; b2 += 256){
      __hip_atomic_store(&bar[(4*GB + phase*GB + b2)*4], 1,
                         __ATOMIC_RELEASE, __HIP_MEMORY_SCOPE_AGENT);
    }
    __syncthreads();
  } else if (spin){
    if (threadIdx.x == 0){
      while (__hip_atomic_load(&bar[(4*GB + phase*GB + blockIdx.x)*4],
                               __ATOMIC_ACQUIRE, __HIP_MEMORY_SCOPE_AGENT) == 0){
        __builtin_amdgcn_s_sleep(4);
      }
    }
    __syncthreads();
  }
}

// ---------------------------------------------------------------------------
// One fused kernel, plain launch, 512 blocks x 256 threads, 5 phases.
// Phase math identical to the r2/r4/r5-verified versions; BN stats now go
// through store/reduce (pstatC/pstatD) instead of global atomics.
// ---------------------------------------------------------------------------
__global__ __launch_bounds__(256, 2) void fused_all(
    const float* __restrict__ pos,
    const float* __restrict__ weights,
    const float* __restrict__ kpos,
    const float* __restrict__ conv_w,
    const float* __restrict__ bn_g,  const float* __restrict__ bn_b,
    const float* __restrict__ w1,    const float* __restrict__ b1,
    const float* __restrict__ bn1_g, const float* __restrict__ bn1_b,
    const float* __restrict__ w2,    const float* __restrict__ b2,
    float* __restrict__ out,
    _Float16* __restrict__ cwh,
    float* __restrict__ part,
    float* __restrict__ z,
    float* __restrict__ y,
    float* __restrict__ h,
    float* __restrict__ pstatC,   // [512][64]  per-block ch-sum/sumsq
    float* __restrict__ pstatD,   // [256][256] per-block h-sum/sumsq
    int* __restrict__ bar)
{
  __shared__ __align__(16) char smem[40960];
  int bid = blockIdx.x;
  int tid = threadIdx.x;

  // ======== Phase A: comp_w f16 producer — 384 blocks ========
  if (bid < 384){
    float* cwl = (float*)smem;     // 12 KB conv_w k-slice
    int kt  = bid % 3;
    int sub = (bid/3)&7, nc = (bid/24)&3, b = bid/96;

    const float4* cs = (const float4*)(conv_w + kt*3*C*C);
    float4* cd = (float4*)cwl;
    for (int v = tid; v < 768; v += 256) cd[v] = cs[v];

    int nl = tid & 31, dq = tid >> 5;
    int row = ((b*4 + nc)*8 + sub)*32 + nl;
    float wreg[32];
    const float4* wr = (const float4*)(weights + (size_t)row*C);
    #pragma unroll
    for (int j = 0; j < 8; ++j){
      float4 t = wr[j];
      wreg[4*j]=t.x; wreg[4*j+1]=t.y; wreg[4*j+2]=t.z; wreg[4*j+3]=t.w;
    }
    __syncthreads();

    _Float16* outb = cwh + (size_t)((b*4+nc)*8 + sub)*CHUNK_F16;
    const float4* cv = (const float4*)cwl;
    #pragma unroll
    for (int kl = 0; kl < 3; ++kl){
      float a0=0.f, a1=0.f, a2=0.f, a3=0.f;
      #pragma unroll
      for (int c = 0; c < C; ++c){
        float4 t = cv[kl*256 + c*8 + dq];
        a0 += wreg[c]*t.x; a1 += wreg[c]*t.y; a2 += wreg[c]*t.z; a3 += wreg[c]*t.w;
      }
      int k = kt*3 + kl;
      outb[(dq*4+0)*KPAD + k*32 + nl] = (_Float16)a0;
      outb[(dq*4+1)*KPAD + k*32 + nl] = (_Float16)a1;
      outb[(dq*4+2)*KPAD + k*32 + nl] = (_Float16)a2;
      outb[(dq*4+3)*KPAD + k*32 + nl] = (_Float16)a3;
    }
  }
  gridbar(bar, 0, true);

  // ======== Phase B: flash-style MFMA Gaussian mixture — all 512 blocks ====
  {
    _Float16* km = (_Float16*)smem;            // [i][K] 18944 B
    _Float16* cw = (_Float16*)(smem + 18944);  // [c][K] 18944 B
    float* pnl   = (float*)(smem + 37888);     // 2 KB
    int nc = bid & 3, it = (bid>>2)&31, b = bid>>7;
    int lane = tid & 63, wid = tid >> 6;
    int i0 = (wid>>1)*16, c0 = (wid&1)*16;
    int mm = lane & 15, quad = lane >> 4;

    const float* pbase = pos + (size_t)(b*NN + nc*NCH)*2;
    for (int v = tid; v < NCH*2; v += 256) pnl[v] = pbase[v];

    int ig = tid >> 3, np = tid & 7;
    float pix = pos[(size_t)(b*NN + it*32 + ig)*2];
    float piy = pos[(size_t)(b*NN + it*32 + ig)*2 + 1];
    float kx[KK], ky[KK];
    #pragma unroll
    for (int k = 0; k < KK; ++k){ kx[k] = kpos[2*k]; ky[k] = kpos[2*k+1]; }

    f32x4 acc = {0.f,0.f,0.f,0.f};
    __syncthreads();

    for (int s = 0; s < 8; ++s){
      const float4* srcs = (const float4*)(cwh + (size_t)((b*4+nc)*8 + s)*CHUNK_F16);
      float4* dst = (float4*)cw;
      for (int v = tid; v < CHUNK_F16/8; v += 256) dst[v] = srcs[v];

      float dx[4], dy[4];
      #pragma unroll
      for (int jj = 0; jj < 4; ++jj){
        int nl = np*4 + jj;
        dx[jj] = pix - pnl[2*(s*32+nl)];
        dy[jj] = piy - pnl[2*(s*32+nl)+1];
      }
      #pragma unroll
      for (int k = 0; k < KK; ++k){
        f16x4 ev;
        #pragma unroll
        for (int jj = 0; jj < 4; ++jj){
          float ddx = dx[jj]-kx[k], ddy = dy[jj]-ky[k];
          ev[jj] = (_Float16)__expf(-0.5f*(ddx*ddx + ddy*ddy));
        }
        *(f16x4*)&km[ig*KPAD + k*32 + np*4] = ev;
      }
      __syncthreads();

      #pragma unroll
      for (int ks = 0; ks < 9; ++ks){
        f16x8 a  = *(const f16x8*)&km[(i0+mm)*KPAD + ks*32 + quad*8];
        f16x8 bf = *(const f16x8*)&cw[(c0+mm)*KPAD + ks*32 + quad*8];
        acc = __builtin_amdgcn_mfma_f32_16x16x32_f16(a, bf, acc, 0, 0, 0);
      }
      __syncthreads();
    }

    int grow0 = b*NN + it*32 + i0;
    #pragma unroll
    for (int r = 0; r < 4; ++r){
      int grow = grow0 + quad*4 + r;
      part[((size_t)nc*M + grow)*C + c0 + mm] = acc[r];
    }
  }
  gridbar(bar, 1, true);

  // ======== Phase C: z = leaky(sum part); per-block ch stats -> pstatC =====
  {
    float* ls1 = (float*)smem;    // [32] sum, then [32] sumsq
    float* ls2 = ls1 + C;
    if (tid < 2*C) ls1[tid] = 0.f;
    __syncthreads();
    size_t idx = (size_t)bid*256 + tid;
    float s = 0.f;
    #pragma unroll
    for (int p = 0; p < SCH; ++p) s += part[(size_t)p*M*C + idx];
    s = leaky(s);
    z[idx] = s;
    atomicAdd(&ls1[tid & (C-1)], s);      // LDS atomics: cheap
    atomicAdd(&ls2[tid & (C-1)], s*s);
    __syncthreads();
    if (tid < 2*C) pstatC[(size_t)bid*64 + tid] = ls1[tid];  // plain store
  }
  gridbar(bar, 2, true);

  // ======== Phase D: BN + residual + MLP layer 1 — 256 blocks ======
  if (bid < 256){
    float* w1l = (float*)smem;              // 16 KB
    float* yl  = (float*)(smem + 16384);    // 2 KB
    float* lt1 = (float*)(smem + 18432);    // 512 B
    float* lt2 = (float*)(smem + 18944);    // 512 B
    float* sst = (float*)(smem + 19456);    // 64 floats reduced stats
    float* red = (float*)(smem + 19712);    // 4x64 chunk partials
    int row0 = bid * 16;

    // reduce pstatC (512x64) redundantly per block: coalesced LLC reads
    {
      int col = tid & 63, ch = tid >> 6;    // 4 chunks x 128 rows
      float a0=0.f,a1=0.f,a2=0.f,a3=0.f;
      int rbase = ch*128;
      for (int r = 0; r < 128; r += 4){
        a0 += pstatC[(size_t)(rbase+r+0)*64 + col];
        a1 += pstatC[(size_t)(rbase+r+1)*64 + col];
        a2 += pstatC[(size_t)(rbase+r+2)*64 + col];
        a3 += pstatC[(size_t)(rbase+r+3)*64 + col];
      }
      red[ch*64 + col] = (a0+a1)+(a2+a3);
    }
    for (int i = tid; i < C*CM; i += 256) w1l[i] = w1[i];
    if (tid < CM){ lt1[tid]=0.f; lt2[tid]=0.f; }
    __syncthreads();
    if (tid < 64) sst[tid] = red[tid] + red[64+tid] + red[128+tid] + red[192+tid];
    __syncthreads();

    #pragma unroll
    for (int j = 0; j < 2; ++j){
      int e = tid + j*256;
      int c  = e & (C-1);
      int rl = e >> 5;
      float mean = sst[c] * (1.f/M);
      float var  = sst[C + c] * (1.f/M) - mean*mean;
      float sc = bn_g[c] * rsqrtf(var + EPSB);
      float sh = bn_b[c] - mean*sc;
      int row = row0 + rl;
      float v = z[(size_t)row*C + c]*sc + sh + weights[(size_t)row*C + c];
      yl[e] = v;
      y[(size_t)row*C + c] = v;
    }
    __syncthreads();
    #pragma unroll
    for (int j = 0; j < 8; ++j){
      int e = tid + j*256;
      int col = e & (CM-1);
      int rl  = e >> 7;
      float acc = b1[col];
      #pragma unroll
      for (int c = 0; c < C; ++c) acc += yl[rl*C + c] * w1l[c*CM + col];
      acc = leaky(acc);
      h[(size_t)(row0+rl)*CM + col] = acc;
      atomicAdd(&lt1[col], acc);
      atomicAdd(&lt2[col], acc*acc);
    }
    __syncthreads();
    if (tid < CM){
      pstatD[(size_t)bid*256 + tid]       = lt1[tid];   // plain stores
      pstatD[(size_t)bid*256 + CM + tid]  = lt2[tid];
    }
  }
  // blocks >=256 just arrive (they don't run phase E)
  gridbar(bar, 3, bid < 256);
  if (bid >= 256) return;

  // ======== Phase E: BN1 + MLP layer 2 + final residual — 256 blocks =======
  {
    float* w2l = (float*)smem;              // 16 KB
    float* hl  = (float*)(smem + 16384);    // 8 KB
    float* sst = (float*)(smem + 24576);    // 256 floats
    int row0 = bid * 16;

    // reduce pstatD (256x256) redundantly per block
    {
      float a0=0.f,a1=0.f,a2=0.f,a3=0.f;
      for (int r = 0; r < 256; r += 4){
        a0 += pstatD[(size_t)(r+0)*256 + tid];
        a1 += pstatD[(size_t)(r+1)*256 + tid];
        a2 += pstatD[(size_t)(r+2)*256 + tid];
        a3 += pstatD[(size_t)(r+3)*256 + tid];
      }
      sst[tid] = (a0+a1)+(a2+a3);
    }
    for (int i = tid; i < CM*C; i += 256) w2l[i] = w2[i];
    __syncthreads();

    #pragma unroll
    for (int j = 0; j < 8; ++j){
      int e = tid + j*256;
      int col = e & (CM-1);
      int rl  = e >> 7;
      float mean = sst[col]*(1.f/M);
      float var  = sst[CM + col]*(1.f/M) - mean*mean;
      float sc = bn1_g[col]*rsqrtf(var + EPSB);
      float sh = bn1_b[col] - mean*sc;
      hl[e] = h[(size_t)(row0+rl)*CM + col]*sc + sh;
    }
    __syncthreads();
    #pragma unroll
    for (int j = 0; j < 2; ++j){
      int e = tid + j*256;
      int c  = e & (C-1);
      int rl = e >> 5;
      float acc = b2[c];
      #pragma unroll
      for (int jj = 0; jj < CM; ++jj) acc += hl[rl*CM + jj] * w2l[jj*C + c];
      int row = row0 + rl;
      out[(size_t)row*C + c] = y[(size_t)row*C + c] + acc;
    }
  }
}

// ---------------------------------------------------------------------------
extern "C" void kernel_launch(void* const* d_in, const int* in_sizes, int n_in,
                              void* d_out, int out_size, void* d_ws, size_t ws_size,
                              hipStream_t stream) {
  const float* positions = (const float*)d_in[0];
  const float* weights   = (const float*)d_in[1];
  const float* kpos      = (const float*)d_in[2];
  const float* conv_w    = (const float*)d_in[3];
  const float* bn_g      = (const float*)d_in[4];
  const float* bn_b      = (const float*)d_in[5];
  const float* w1        = (const float*)d_in[6];
  const float* b1        = (const float*)d_in[7];
  const float* bn1_g     = (const float*)d_in[8];
  const float* bn1_b     = (const float*)d_in[9];
  const float* w2        = (const float*)d_in[10];
  const float* b2        = (const float*)d_in[11];
  float* out = (float*)d_out;

  float* ws = (float*)d_ws;
  size_t off = 0;
  _Float16* cwh = (_Float16*)(ws + off); off += (size_t)128*CHUNK_F16/2;
  float* part   = ws + off; off += (size_t)SCH*M*C;
  float* z      = ws + off; off += (size_t)M*C;
  float* y      = ws + off; off += (size_t)M*C;
  float* h      = ws + off; off += (size_t)M*CM;
  float* pstatC = ws + off; off += (size_t)GB*64;
  float* pstatD = ws + off; off += (size_t)256*256;
  int* bar      = (int*)(ws + off); off += BAR_INTS;

  hipMemsetAsync(bar, 0, BAR_INTS*sizeof(int), stream);
  fused_all<<<GB, 256, 0, stream>>>(
      positions, weights, kpos, conv_w, bn_g, bn_b, w1, b1,
      bn1_g, bn1_b, w2, b2, out, cwh, part, z, y, h, pstatC, pstatD, bar);
}

// Round 7
// 188.073 us; speedup vs baseline: 1.8789x; 1.8789x over previous
//
#include <hip/hip_runtime.h>

#define BB 4
#define NN 1024
#define KK 9
#define C  32
#define CM 128
#define M  (BB*NN)       // 4096 rows
#define EPSB 1e-5f
#define SLOPE 0.01f

#define GB 512           // grid blocks
#define SCH 4            // n-chunks (part slots)
#define NCH 256          // n per chunk
#define KPAD 296         // padded row stride (f16) for comp_w tiles
#define CHUNK_F16 (32*KPAD)   // 9472 f16 per (b,nc,sub) tile

// barrier memory: arrive flag(p,b) at (p*GB+b)*4 ints (16B stride);
// done flag(p,b) at (4*GB + p*GB + b)*4. All zeroed by memset pre-launch.
#define BAR_INTS (2*4*GB*4)

typedef _Float16 f16x8 __attribute__((ext_vector_type(8)));
typedef _Float16 f16x4 __attribute__((ext_vector_type(4)));
typedef float    f32x4 __attribute__((ext_vector_type(4)));

__device__ __forceinline__ float leaky(float x){ return x > 0.f ? x : SLOPE*x; }

// Relaxed-spin grid barrier. r4/r5/r6 evidence: agent-scope acquire loads
// emit buffer_inv (L2 invalidate) and release stores emit buffer_wbl2 PER
// OP on gfx950 — spinning with acquire nukes every XCD's L2 continuously
// (r6: FETCH_SIZE +27%, VALUBusy 3.9%, ~70us/barrier). Here all flag ops
// are RELAXED (agent scope still reaches the coherence point, so
// visibility holds); exactly ONE release fence per block before arrival
// and ONE acquire fence per block after its done-flag — 2 cache-maint ops
// per block per barrier instead of thousands.
__device__ __forceinline__ void gridbar(int* bar, int phase, bool spin){
  __syncthreads();
  if (threadIdx.x == 0){
    __builtin_amdgcn_fence(__ATOMIC_RELEASE, "agent");   // one wbl2
    __hip_atomic_store(&bar[(phase*GB + blockIdx.x)*4], 1,
                       __ATOMIC_RELAXED, __HIP_MEMORY_SCOPE_AGENT);
  }
  if (blockIdx.x == 0){
    int s0 = (phase*GB + threadIdx.x*2)*4;
    for (;;){
      int a = __hip_atomic_load(&bar[s0],   __ATOMIC_RELAXED, __HIP_MEMORY_SCOPE_AGENT);
      int b = __hip_atomic_load(&bar[s0+4], __ATOMIC_RELAXED, __HIP_MEMORY_SCOPE_AGENT);
      if (__syncthreads_count((a + b) < 2) == 0) break;
      __builtin_amdgcn_s_sleep(4);
    }
    if (threadIdx.x == 0)
      __builtin_amdgcn_fence(__ATOMIC_ACQ_REL, "agent"); // one inv+wbl2
    __syncthreads();
    for (int b2 = threadIdx.x; b2 < GB; b2 += 256){
      __hip_atomic_store(&bar[(4*GB + phase*GB + b2)*4], 1,
                         __ATOMIC_RELAXED, __HIP_MEMORY_SCOPE_AGENT);
    }
    __syncthreads();
  } else if (spin){
    if (threadIdx.x == 0){
      while (__hip_atomic_load(&bar[(4*GB + phase*GB + blockIdx.x)*4],
                               __ATOMIC_RELAXED, __HIP_MEMORY_SCOPE_AGENT) == 0){
        __builtin_amdgcn_s_sleep(4);
      }
      __builtin_amdgcn_fence(__ATOMIC_ACQUIRE, "agent"); // one inv
    }
    __syncthreads();
  }
}

// ---------------------------------------------------------------------------
// One fused kernel, plain launch, 512 blocks x 256 threads, 5 phases.
// Phase math identical to the r2/r4/r5/r6-verified versions.
// ---------------------------------------------------------------------------
__global__ __launch_bounds__(256, 2) void fused_all(
    const float* __restrict__ pos,
    const float* __restrict__ weights,
    const float* __restrict__ kpos,
    const float* __restrict__ conv_w,
    const float* __restrict__ bn_g,  const float* __restrict__ bn_b,
    const float* __restrict__ w1,    const float* __restrict__ b1,
    const float* __restrict__ bn1_g, const float* __restrict__ bn1_b,
    const float* __restrict__ w2,    const float* __restrict__ b2,
    float* __restrict__ out,
    _Float16* __restrict__ cwh,
    float* __restrict__ part,
    float* __restrict__ z,
    float* __restrict__ y,
    float* __restrict__ h,
    float* __restrict__ pstatC,   // [512][64]  per-block ch-sum/sumsq
    float* __restrict__ pstatD,   // [256][256] per-block h-sum/sumsq
    int* __restrict__ bar)
{
  __shared__ __align__(16) char smem[40960];
  int bid = blockIdx.x;
  int tid = threadIdx.x;

  // ======== Phase A: comp_w f16 producer — 384 blocks ========
  if (bid < 384){
    float* cwl = (float*)smem;     // 12 KB conv_w k-slice
    int kt  = bid % 3;
    int sub = (bid/3)&7, nc = (bid/24)&3, b = bid/96;

    const float4* cs = (const float4*)(conv_w + kt*3*C*C);
    float4* cd = (float4*)cwl;
    for (int v = tid; v < 768; v += 256) cd[v] = cs[v];

    int nl = tid & 31, dq = tid >> 5;
    int row = ((b*4 + nc)*8 + sub)*32 + nl;
    float wreg[32];
    const float4* wr = (const float4*)(weights + (size_t)row*C);
    #pragma unroll
    for (int j = 0; j < 8; ++j){
      float4 t = wr[j];
      wreg[4*j]=t.x; wreg[4*j+1]=t.y; wreg[4*j+2]=t.z; wreg[4*j+3]=t.w;
    }
    __syncthreads();

    _Float16* outb = cwh + (size_t)((b*4+nc)*8 + sub)*CHUNK_F16;
    const float4* cv = (const float4*)cwl;
    #pragma unroll
    for (int kl = 0; kl < 3; ++kl){
      float a0=0.f, a1=0.f, a2=0.f, a3=0.f;
      #pragma unroll
      for (int c = 0; c < C; ++c){
        float4 t = cv[kl*256 + c*8 + dq];
        a0 += wreg[c]*t.x; a1 += wreg[c]*t.y; a2 += wreg[c]*t.z; a3 += wreg[c]*t.w;
      }
      int k = kt*3 + kl;
      outb[(dq*4+0)*KPAD + k*32 + nl] = (_Float16)a0;
      outb[(dq*4+1)*KPAD + k*32 + nl] = (_Float16)a1;
      outb[(dq*4+2)*KPAD + k*32 + nl] = (_Float16)a2;
      outb[(dq*4+3)*KPAD + k*32 + nl] = (_Float16)a3;
    }
  }
  gridbar(bar, 0, true);

  // ======== Phase B: flash-style MFMA Gaussian mixture — all 512 blocks ====
  {
    _Float16* km = (_Float16*)smem;            // [i][K] 18944 B
    _Float16* cw = (_Float16*)(smem + 18944);  // [c][K] 18944 B
    float* pnl   = (float*)(smem + 37888);     // 2 KB
    int nc = bid & 3, it = (bid>>2)&31, b = bid>>7;
    int lane = tid & 63, wid = tid >> 6;
    int i0 = (wid>>1)*16, c0 = (wid&1)*16;
    int mm = lane & 15, quad = lane >> 4;

    const float* pbase = pos + (size_t)(b*NN + nc*NCH)*2;
    for (int v = tid; v < NCH*2; v += 256) pnl[v] = pbase[v];

    int ig = tid >> 3, np = tid & 7;
    float pix = pos[(size_t)(b*NN + it*32 + ig)*2];
    float piy = pos[(size_t)(b*NN + it*32 + ig)*2 + 1];
    float kx[KK], ky[KK];
    #pragma unroll
    for (int k = 0; k < KK; ++k){ kx[k] = kpos[2*k]; ky[k] = kpos[2*k+1]; }

    f32x4 acc = {0.f,0.f,0.f,0.f};
    __syncthreads();

    for (int s = 0; s < 8; ++s){
      const float4* srcs = (const float4*)(cwh + (size_t)((b*4+nc)*8 + s)*CHUNK_F16);
      float4* dst = (float4*)cw;
      for (int v = tid; v < CHUNK_F16/8; v += 256) dst[v] = srcs[v];

      float dx[4], dy[4];
      #pragma unroll
      for (int jj = 0; jj < 4; ++jj){
        int nl = np*4 + jj;
        dx[jj] = pix - pnl[2*(s*32+nl)];
        dy[jj] = piy - pnl[2*(s*32+nl)+1];
      }
      #pragma unroll
      for (int k = 0; k < KK; ++k){
        f16x4 ev;
        #pragma unroll
        for (int jj = 0; jj < 4; ++jj){
          float ddx = dx[jj]-kx[k], ddy = dy[jj]-ky[k];
          ev[jj] = (_Float16)__expf(-0.5f*(ddx*ddx + ddy*ddy));
        }
        *(f16x4*)&km[ig*KPAD + k*32 + np*4] = ev;
      }
      __syncthreads();

      #pragma unroll
      for (int ks = 0; ks < 9; ++ks){
        f16x8 a  = *(const f16x8*)&km[(i0+mm)*KPAD + ks*32 + quad*8];
        f16x8 bf = *(const f16x8*)&cw[(c0+mm)*KPAD + ks*32 + quad*8];
        acc = __builtin_amdgcn_mfma_f32_16x16x32_f16(a, bf, acc, 0, 0, 0);
      }
      __syncthreads();
    }

    int grow0 = b*NN + it*32 + i0;
    #pragma unroll
    for (int r = 0; r < 4; ++r){
      int grow = grow0 + quad*4 + r;
      part[((size_t)nc*M + grow)*C + c0 + mm] = acc[r];
    }
  }
  gridbar(bar, 1, true);

  // ======== Phase C: z = leaky(sum part); per-block ch stats -> pstatC =====
  {
    float* ls1 = (float*)smem;    // [32] sum, then [32] sumsq
    float* ls2 = ls1 + C;
    if (tid < 2*C) ls1[tid] = 0.f;
    __syncthreads();
    size_t idx = (size_t)bid*256 + tid;
    float s = 0.f;
    #pragma unroll
    for (int p = 0; p < SCH; ++p) s += part[(size_t)p*M*C + idx];
    s = leaky(s);
    z[idx] = s;
    atomicAdd(&ls1[tid & (C-1)], s);      // LDS atomics: cheap
    atomicAdd(&ls2[tid & (C-1)], s*s);
    __syncthreads();
    if (tid < 2*C) pstatC[(size_t)bid*64 + tid] = ls1[tid];  // plain store
  }
  gridbar(bar, 2, true);

  // ======== Phase D: BN + residual + MLP layer 1 — 256 blocks ======
  if (bid < 256){
    float* w1l = (float*)smem;              // 16 KB
    float* yl  = (float*)(smem + 16384);    // 2 KB
    float* lt1 = (float*)(smem + 18432);    // 512 B
    float* lt2 = (float*)(smem + 18944);    // 512 B
    float* sst = (float*)(smem + 19456);    // 64 floats reduced stats
    float* red = (float*)(smem + 19712);    // 4x64 chunk partials
    int row0 = bid * 16;

    // reduce pstatC (512x64) redundantly per block: coalesced LLC reads
    {
      int col = tid & 63, ch = tid >> 6;    // 4 chunks x 128 rows
      float a0=0.f,a1=0.f,a2=0.f,a3=0.f;
      int rbase = ch*128;
      for (int r = 0; r < 128; r += 4){
        a0 += pstatC[(size_t)(rbase+r+0)*64 + col];
        a1 += pstatC[(size_t)(rbase+r+1)*64 + col];
        a2 += pstatC[(size_t)(rbase+r+2)*64 + col];
        a3 += pstatC[(size_t)(rbase+r+3)*64 + col];
      }
      red[ch*64 + col] = (a0+a1)+(a2+a3);
    }
    for (int i = tid; i < C*CM; i += 256) w1l[i] = w1[i];
    if (tid < CM){ lt1[tid]=0.f; lt2[tid]=0.f; }
    __syncthreads();
    if (tid < 64) sst[tid] = red[tid] + red[64+tid] + red[128+tid] + red[192+tid];
    __syncthreads();

    #pragma unroll
    for (int j = 0; j < 2; ++j){
      int e = tid + j*256;
      int c  = e & (C-1);
      int rl = e >> 5;
      float mean = sst[c] * (1.f/M);
      float var  = sst[C + c] * (1.f/M) - mean*mean;
      float sc = bn_g[c] * rsqrtf(var + EPSB);
      float sh = bn_b[c] - mean*sc;
      int row = row0 + rl;
      float v = z[(size_t)row*C + c]*sc + sh + weights[(size_t)row*C + c];
      yl[e] = v;
      y[(size_t)row*C + c] = v;
    }
    __syncthreads();
    #pragma unroll
    for (int j = 0; j < 8; ++j){
      int e = tid + j*256;
      int col = e & (CM-1);
      int rl  = e >> 7;
      float acc = b1[col];
      #pragma unroll
      for (int c = 0; c < C; ++c) acc += yl[rl*C + c] * w1l[c*CM + col];
      acc = leaky(acc);
      h[(size_t)(row0+rl)*CM + col] = acc;
      atomicAdd(&lt1[col], acc);
      atomicAdd(&lt2[col], acc*acc);
    }
    __syncthreads();
    if (tid < CM){
      pstatD[(size_t)bid*256 + tid]       = lt1[tid];   // plain stores
      pstatD[(size_t)bid*256 + CM + tid]  = lt2[tid];
    }
  }
  // blocks >=256 just arrive (they don't run phase E)
  gridbar(bar, 3, bid < 256);
  if (bid >= 256) return;

  // ======== Phase E: BN1 + MLP layer 2 + final residual — 256 blocks =======
  {
    float* w2l = (float*)smem;              // 16 KB
    float* hl  = (float*)(smem + 16384);    // 8 KB
    float* sst = (float*)(smem + 24576);    // 256 floats
    int row0 = bid * 16;

    // reduce pstatD (256x256) redundantly per block
    {
      float a0=0.f,a1=0.f,a2=0.f,a3=0.f;
      for (int r = 0; r < 256; r += 4){
        a0 += pstatD[(size_t)(r+0)*256 + tid];
        a1 += pstatD[(size_t)(r+1)*256 + tid];
        a2 += pstatD[(size_t)(r+2)*256 + tid];
        a3 += pstatD[(size_t)(r+3)*256 + tid];
      }
      sst[tid] = (a0+a1)+(a2+a3);
    }
    for (int i = tid; i < CM*C; i += 256) w2l[i] = w2[i];
    __syncthreads();

    #pragma unroll
    for (int j = 0; j < 8; ++j){
      int e = tid + j*256;
      int col = e & (CM-1);
      int rl  = e >> 7;
      float mean = sst[col]*(1.f/M);
      float var  = sst[CM + col]*(1.f/M) - mean*mean;
      float sc = bn1_g[col]*rsqrtf(var + EPSB);
      float sh = bn1_b[col] - mean*sc;
      hl[e] = h[(size_t)(row0+rl)*CM + col]*sc + sh;
    }
    __syncthreads();
    #pragma unroll
    for (int j = 0; j < 2; ++j){
      int e = tid + j*256;
      int c  = e & (C-1);
      int rl = e >> 5;
      float acc = b2[c];
      #pragma unroll
      for (int jj = 0; jj < CM; ++jj) acc += hl[rl*CM + jj] * w2l[jj*C + c];
      int row = row0 + rl;
      out[(size_t)row*C + c] = y[(size_t)row*C + c] + acc;
    }
  }
}

// ---------------------------------------------------------------------------
extern "C" void kernel_launch(void* const* d_in, const int* in_sizes, int n_in,
                              void* d_out, int out_size, void* d_ws, size_t ws_size,
                              hipStream_t stream) {
  const float* positions = (const float*)d_in[0];
  const float* weights   = (const float*)d_in[1];
  const float* kpos      = (const float*)d_in[2];
  const float* conv_w    = (const float*)d_in[3];
  const float* bn_g      = (const float*)d_in[4];
  const float* bn_b      = (const float*)d_in[5];
  const float* w1        = (const float*)d_in[6];
  const float* b1        = (const float*)d_in[7];
  const float* bn1_g     = (const float*)d_in[8];
  const float* bn1_b     = (const float*)d_in[9];
  const float* w2        = (const float*)d_in[10];
  const float* b2        = (const float*)d_in[11];
  float* out = (float*)d_out;

  float* ws = (float*)d_ws;
  size_t off = 0;
  _Float16* cwh = (_Float16*)(ws + off); off += (size_t)128*CHUNK_F16/2;
  float* part   = ws + off; off += (size_t)SCH*M*C;
  float* z      = ws + off; off += (size_t)M*C;
  float* y      = ws + off; off += (size_t)M*C;
  float* h      = ws + off; off += (size_t)M*CM;
  float* pstatC = ws + off; off += (size_t)GB*64;
  float* pstatD = ws + off; off += (size_t)256*256;
  int* bar      = (int*)(ws + off); off += BAR_INTS;

  hipMemsetAsync(bar, 0, BAR_INTS*sizeof(int), stream);
  fused_all<<<GB, 256, 0, stream>>>(
      positions, weights, kpos, conv_w, bn_g, bn_b, w1, b1,
      bn1_g, bn1_b, w2, b2, out, cwh, part, z, y, h, pstatC, pstatD, bar);
}